// Round 6
// baseline (80.282 us; speedup 1.0000x reference)
//
#include <hip/hip_runtime.h>
#include <math.h>

typedef unsigned long long u64;

#define S_DIM 1023
#define B_DIM 64
#define I_DIM 1024
#define CTX_DIM 784
#define CTX4 196          // CTX_DIM / 4
#define NWROWS 16         // 2^M buckets
#define NTASK (S_DIM * NWROWS)

#define LR_C 0.01f
#define WC_C 5.0f
#define LO_C (-6.906754778648554f)
#define HI_C ( 6.906754778648554f)

__device__ __forceinline__ float dot4(float4 a, float4 b) {
    return a.x * b.x + a.y * b.y + a.z * b.z + a.w * b.w;
}

__device__ __forceinline__ float4 upd4(float4 w, float4 a, float c) {
    float4 r;
    r.x = fminf(fmaxf(w.x - c * a.x, -WC_C), WC_C);
    r.y = fminf(fmaxf(w.y - c * a.y, -WC_C), WC_C);
    r.z = fminf(fmaxf(w.z - c * a.z, -WC_C), WC_C);
    r.w = fminf(fmaxf(w.w - c * a.w, -WC_C), WC_C);
    return r;
}

// ---------------- kernel A: context -> float4-transposed layout + bias row ----------------
__global__ __launch_bounds__(256) void prep_kernel(
    const float* __restrict__ context,   // [B, CTX]
    const float* __restrict__ bias,      // [1]
    float4* __restrict__ ctxT4,          // [CTX4][B]
    float* __restrict__ out_logits)      // [B, S+1]
{
    int g = blockIdx.x * 256 + threadIdx.x;
    int k4 = g >> 6;
    int b  = g & 63;
    ctxT4[g] = *(const float4*)(context + (size_t)b * CTX_DIM + k4 * 4);
    if (g < B_DIM) out_logits[(size_t)g * (S_DIM + 1)] = bias[0];
}

// ---------------- kernel B: halfspace hash -> masks + lastb table ----------------
__global__ __launch_bounds__(256) void gln_idx_kernel(
    const float* __restrict__ cm,        // [S, 4, CTX]
    const float* __restrict__ cb,        // [S, 4]
    const float4* __restrict__ ctxT4,    // [CTX4][B]
    u64* __restrict__ mask_g,            // [S*16]
    int* __restrict__ lastb_g)           // [S*16]
{
    __shared__ float4 cm4[4 * CTX4];
    __shared__ float  red[4][4][64];
    __shared__ int    bits[4][64];
    __shared__ float  cb_lds[4];

    const int s = blockIdx.x;
    const int t = threadIdx.x;

    const float4* src = (const float4*)(cm + (size_t)s * 4 * CTX_DIM);
    for (int j = t; j < 4 * CTX4; j += 256) cm4[j] = src[j];
    if (t < 4) cb_lds[t] = cb[s * 4 + t];
    __syncthreads();

    const int b = t & 63;
    const int q = t >> 6;
    float a0 = 0.f, a1 = 0.f, a2 = 0.f, a3 = 0.f;
    const int k0 = q * 49;
    #pragma unroll 7
    for (int kk = 0; kk < 49; ++kk) {
        int k4 = k0 + kk;
        float4 c4 = ctxT4[k4 * 64 + b];
        a0 += dot4(cm4[k4], c4);
        a1 += dot4(cm4[CTX4 + k4], c4);
        a2 += dot4(cm4[2 * CTX4 + k4], c4);
        a3 += dot4(cm4[3 * CTX4 + k4], c4);
    }
    red[q][0][b] = a0;
    red[q][1][b] = a1;
    red[q][2][b] = a2;
    red[q][3][b] = a3;
    __syncthreads();

    {
        int m = t >> 6, bb = t & 63;
        float sum = red[0][m][bb] + red[1][m][bb] + red[2][m][bb] + red[3][m][bb];
        bits[m][bb] = (sum > cb_lds[m]) ? 1 : 0;
    }
    __syncthreads();

    if (t < B_DIM) {   // wave 0: lane = b
        int v = bits[0][t] + 2 * bits[1][t] + 4 * bits[2][t] + 8 * bits[3][t];
        u64 my = 0;
        #pragma unroll
        for (int kk = 0; kk < NWROWS; ++kk) {
            u64 mk = __ballot(v == kk);
            if (t == kk) my = mk;
        }
        if (t < NWROWS) {
            mask_g[s * NWROWS + t]  = my;
            lastb_g[s * NWROWS + t] = my ? (63 - __clzll(my)) : -1;
        }
    }
}

// ---------------- kernel C: dots only (wave per row, 4-member batched loads) ----------------
__global__ __launch_bounds__(256) void gln_dots_kernel(
    const float* __restrict__ logit,     // [B, I]
    const float* __restrict__ target,    // [B]
    const float* __restrict__ weights,   // [S, 16, I]
    const u64*   __restrict__ mask_g,    // [S*16]
    float* __restrict__ out_logits,      // [B, S+1]
    float* __restrict__ coef_g)          // [S*16]
{
    const int wv = threadIdx.x >> 6;
    const int ln = threadIdx.x & 63;
    const int task = blockIdx.x * 4 + wv;
    const int s = task >> 4;

    u64 m = mask_g[task];
    if (!m) return;                       // wave-uniform
    const int last = 63 - __clzll(m);

    const float4* wr = (const float4*)weights + (size_t)task * 256;
    float4 w0 = wr[ln], w1 = wr[ln + 64], w2 = wr[ln + 128], w3 = wr[ln + 192];

    while (m) {
        // extract up to 4 members (wave-uniform scalars)
        int b0 = -1, b1 = -1, b2 = -1, b3 = -1;
        b0 = __builtin_ctzll(m); m &= m - 1;
        if (m) { b1 = __builtin_ctzll(m); m &= m - 1;
            if (m) { b2 = __builtin_ctzll(m); m &= m - 1;
                if (m) { b3 = __builtin_ctzll(m); m &= m - 1; } } }

        // issue ALL logit loads before any reduce
        float4 a00, a01, a02, a03, a10, a11, a12, a13;
        float4 a20, a21, a22, a23, a30, a31, a32, a33;
        {
            const float4* lg = (const float4*)logit + (size_t)b0 * 256;
            a00 = lg[ln]; a01 = lg[ln+64]; a02 = lg[ln+128]; a03 = lg[ln+192];
        }
        if (b1 >= 0) {
            const float4* lg = (const float4*)logit + (size_t)b1 * 256;
            a10 = lg[ln]; a11 = lg[ln+64]; a12 = lg[ln+128]; a13 = lg[ln+192];
        }
        if (b2 >= 0) {
            const float4* lg = (const float4*)logit + (size_t)b2 * 256;
            a20 = lg[ln]; a21 = lg[ln+64]; a22 = lg[ln+128]; a23 = lg[ln+192];
        }
        if (b3 >= 0) {
            const float4* lg = (const float4*)logit + (size_t)b3 * 256;
            a30 = lg[ln]; a31 = lg[ln+64]; a32 = lg[ln+128]; a33 = lg[ln+192];
        }

        // process the (up to) 4 members; independent chains overlap
        {
            float acc = dot4(a00,w0) + dot4(a01,w1) + dot4(a02,w2) + dot4(a03,w3);
            #pragma unroll
            for (int off = 32; off; off >>= 1) acc += __shfl_xor(acc, off, 64);
            float o = fminf(fmaxf(acc, LO_C), HI_C);
            if (ln == 0) {
                out_logits[(size_t)b0 * (S_DIM + 1) + s + 1] = o;
                if (b0 == last)
                    coef_g[task] = LR_C * (1.0f / (1.0f + expf(-o)) - target[b0]);
            }
        }
        if (b1 >= 0) {
            float acc = dot4(a10,w0) + dot4(a11,w1) + dot4(a12,w2) + dot4(a13,w3);
            #pragma unroll
            for (int off = 32; off; off >>= 1) acc += __shfl_xor(acc, off, 64);
            float o = fminf(fmaxf(acc, LO_C), HI_C);
            if (ln == 0) {
                out_logits[(size_t)b1 * (S_DIM + 1) + s + 1] = o;
                if (b1 == last)
                    coef_g[task] = LR_C * (1.0f / (1.0f + expf(-o)) - target[b1]);
            }
        }
        if (b2 >= 0) {
            float acc = dot4(a20,w0) + dot4(a21,w1) + dot4(a22,w2) + dot4(a23,w3);
            #pragma unroll
            for (int off = 32; off; off >>= 1) acc += __shfl_xor(acc, off, 64);
            float o = fminf(fmaxf(acc, LO_C), HI_C);
            if (ln == 0) {
                out_logits[(size_t)b2 * (S_DIM + 1) + s + 1] = o;
                if (b2 == last)
                    coef_g[task] = LR_C * (1.0f / (1.0f + expf(-o)) - target[b2]);
            }
        }
        if (b3 >= 0) {
            float acc = dot4(a30,w0) + dot4(a31,w1) + dot4(a32,w2) + dot4(a33,w3);
            #pragma unroll
            for (int off = 32; off; off >>= 1) acc += __shfl_xor(acc, off, 64);
            float o = fminf(fmaxf(acc, LO_C), HI_C);
            if (ln == 0) {
                out_logits[(size_t)b3 * (S_DIM + 1) + s + 1] = o;
                if (b3 == last)
                    coef_g[task] = LR_C * (1.0f / (1.0f + expf(-o)) - target[b3]);
            }
        }
    }
}

// ---------------- kernel D: pure streaming update ----------------
__global__ __launch_bounds__(256) void upd_kernel(
    const float* __restrict__ logit,     // [B, I]
    const float* __restrict__ weights,   // [S*16*I]
    const int*   __restrict__ lastb_g,   // [S*16]
    const float* __restrict__ coef_g,    // [S*16]
    float* __restrict__ new_weights)
{
    const int total = NTASK * 256;       // float4 count
    const int stride = gridDim.x * 256;
    for (int g = blockIdx.x * 256 + threadIdx.x; g < total; g += stride) {
        const int task = g >> 8;
        const int off  = g & 255;
        const int lb   = lastb_g[task];          // wave-uniform (256 f4 per task)
        float4 w = ((const float4*)weights)[g];
        float4 r;
        if (lb < 0) {
            r = w;
        } else {
            const float c = coef_g[task];
            float4 a = ((const float4*)logit)[lb * 256 + off];
            r = upd4(w, a, c);
        }
        ((float4*)new_weights)[g] = r;
    }
}

extern "C" void kernel_launch(void* const* d_in, const int* in_sizes, int n_in,
                              void* d_out, int out_size, void* d_ws, size_t ws_size,
                              hipStream_t stream) {
    const float* logit   = (const float*)d_in[0];   // [B, I, 1]
    const float* context = (const float*)d_in[1];   // [B, CTX]
    const float* target  = (const float*)d_in[2];   // [B, 1]
    const float* cm      = (const float*)d_in[3];   // [1, S, 4, CTX]
    const float* cb      = (const float*)d_in[4];   // [1, S, 4, 1]
    const float* weights = (const float*)d_in[5];   // [1, S, 16, I]
    const float* bias    = (const float*)d_in[6];   // [1]

    float* out_logits  = (float*)d_out;                       // [B, S+1]
    float* new_weights = out_logits + (size_t)B_DIM * (S_DIM + 1);

    char* ws = (char*)d_ws;
    float4* ctxT4 = (float4*)ws;                 ws += (size_t)CTX4 * B_DIM * 16;   // 200704
    u64*    mask_g  = (u64*)ws;                  ws += (size_t)NTASK * 8;
    int*    lastb_g = (int*)ws;                  ws += (size_t)NTASK * 4;
    float*  coef_g  = (float*)ws;

    prep_kernel<<<CTX4 * B_DIM / 256, 256, 0, stream>>>(context, bias, ctxT4, out_logits);
    gln_idx_kernel<<<S_DIM, 256, 0, stream>>>(cm, cb, ctxT4, mask_g, lastb_g);
    gln_dots_kernel<<<NTASK / 4, 256, 0, stream>>>(logit, target, weights, mask_g,
                                                   out_logits, coef_g);
    upd_kernel<<<8192, 256, 0, stream>>>(logit, weights, lastb_g, coef_g, new_weights);
}

// Round 7
// 59.567 us; speedup vs baseline: 1.3478x; 1.3478x over previous
//
#include <hip/hip_runtime.h>
#include <math.h>

typedef unsigned long long u64;

#define S_DIM 1023
#define B_DIM 64
#define I_DIM 1024
#define CTX_DIM 784
#define CTX4 196          // CTX_DIM / 4
#define NWROWS 16         // 2^M buckets
#define NTASK (S_DIM * NWROWS)

#define LR_C 0.01f
#define WC_C 5.0f
#define LO_C (-6.906754778648554f)
#define HI_C ( 6.906754778648554f)

__device__ __forceinline__ float dot4(float4 a, float4 b) {
    return a.x * b.x + a.y * b.y + a.z * b.z + a.w * b.w;
}

__device__ __forceinline__ float4 upd4(float4 w, float4 a, float c) {
    float4 r;
    r.x = fminf(fmaxf(w.x - c * a.x, -WC_C), WC_C);
    r.y = fminf(fmaxf(w.y - c * a.y, -WC_C), WC_C);
    r.z = fminf(fmaxf(w.z - c * a.z, -WC_C), WC_C);
    r.w = fminf(fmaxf(w.w - c * a.w, -WC_C), WC_C);
    return r;
}

// ---------------- kernel A: context -> float4-transposed layout + bias row ----------------
__global__ __launch_bounds__(256) void prep_kernel(
    const float* __restrict__ context,   // [B, CTX]
    const float* __restrict__ bias,      // [1]
    float4* __restrict__ ctxT4,          // [CTX4][B]
    float* __restrict__ out_logits)      // [B, S+1]
{
    int g = blockIdx.x * 256 + threadIdx.x;
    int k4 = g >> 6;
    int b  = g & 63;
    ctxT4[g] = *(const float4*)(context + (size_t)b * CTX_DIM + k4 * 4);
    if (g < B_DIM) out_logits[(size_t)g * (S_DIM + 1)] = bias[0];
}

// ---------------- kernel B: halfspace hash -> membership masks ----------------
// cm addresses are wave-uniform (wave = k-quarter): read from global via the
// scalar path (readfirstlane forces uniformity) -- no LDS staging, no LDS-pipe
// bottleneck (was 4x ds_read_b128 per 16 FMA).
__global__ __launch_bounds__(256) void gln_idx_kernel(
    const float* __restrict__ cm,        // [S, 4, CTX]
    const float* __restrict__ cb,        // [S, 4]
    const float4* __restrict__ ctxT4,    // [CTX4][B]
    u64* __restrict__ mask_g)            // [S*16]
{
    __shared__ float red[4][4][64];      // [q][m][b]
    __shared__ int   bits[4][64];
    __shared__ float cb_lds[4];

    const int s = blockIdx.x;
    const int t = threadIdx.x;
    if (t < 4) cb_lds[t] = cb[s * 4 + t];

    const int b = t & 63;
    const int q = __builtin_amdgcn_readfirstlane(t >> 6);   // k-quarter, uniform
    const float4* cmr = (const float4*)(cm + (size_t)s * 4 * CTX_DIM);  // [4*196] f4

    float a0 = 0.f, a1 = 0.f, a2 = 0.f, a3 = 0.f;
    const int k0 = q * 49;
    #pragma unroll 7
    for (int kk = 0; kk < 49; ++kk) {
        int k4 = k0 + kk;
        float4 c4 = ctxT4[k4 * 64 + b];          // 1KB coalesced (L2)
        float4 m0 = cmr[k4];                     // uniform -> scalar/broadcast load
        float4 m1 = cmr[CTX4 + k4];
        float4 m2 = cmr[2 * CTX4 + k4];
        float4 m3 = cmr[3 * CTX4 + k4];
        a0 += dot4(m0, c4);
        a1 += dot4(m1, c4);
        a2 += dot4(m2, c4);
        a3 += dot4(m3, c4);
    }
    red[q][0][b] = a0;
    red[q][1][b] = a1;
    red[q][2][b] = a2;
    red[q][3][b] = a3;
    __syncthreads();

    {
        int m = t >> 6, bb = t & 63;
        float sum = red[0][m][bb] + red[1][m][bb] + red[2][m][bb] + red[3][m][bb];
        bits[m][bb] = (sum > cb_lds[m]) ? 1 : 0;
    }
    __syncthreads();

    if (t < B_DIM) {   // wave 0: lane = b
        int v = bits[0][t] + 2 * bits[1][t] + 4 * bits[2][t] + 8 * bits[3][t];
        u64 my = 0;
        #pragma unroll
        for (int kk = 0; kk < NWROWS; ++kk) {
            u64 mk = __ballot(v == kk);
            if (t == kk) my = mk;
        }
        if (t < NWROWS) mask_g[s * NWROWS + t] = my;
    }
}

// ---------------- kernel C: fused dots+update, 1 row/wave, 2-member batches ----------------
__global__ __launch_bounds__(256, 4) void gln_row3_kernel(
    const float* __restrict__ logit,     // [B, I]
    const float* __restrict__ target,    // [B]
    const float* __restrict__ weights,   // [S, 16, I]
    const u64*   __restrict__ mask_g,    // [S*16]
    float* __restrict__ out_logits,      // [B, S+1]
    float* __restrict__ new_weights)     // [S, 16, I]
{
    const int wv = threadIdx.x >> 6;
    const int ln = threadIdx.x & 63;
    const int task = blockIdx.x * 4 + wv;
    const int s = task >> 4;

    const float4* wr = (const float4*)weights + (size_t)task * 256;
    float4* dst = (float4*)new_weights + (size_t)task * 256;

    // W row -> registers (4 independent loads in flight immediately)
    float4 w0 = wr[ln], w1 = wr[ln + 64], w2 = wr[ln + 128], w3 = wr[ln + 192];

    u64 m = mask_g[task];
    if (!m) {                              // wave-uniform: verbatim copy
        dst[ln]       = w0;
        dst[ln + 64]  = w1;
        dst[ln + 128] = w2;
        dst[ln + 192] = w3;
        return;
    }
    const int last = 63 - __clzll(m);

    while (m) {
        // extract up to 2 members (wave-uniform scalars)
        const int b0 = __builtin_ctzll(m); m &= m - 1;
        int b1 = -1;
        if (m) { b1 = __builtin_ctzll(m); m &= m - 1; }

        // issue BOTH members' logit loads before any reduce
        const float4* lg0 = (const float4*)logit + (size_t)b0 * 256;
        float4 a00 = lg0[ln], a01 = lg0[ln+64], a02 = lg0[ln+128], a03 = lg0[ln+192];
        float4 a10, a11, a12, a13;
        if (b1 >= 0) {
            const float4* lg1 = (const float4*)logit + (size_t)b1 * 256;
            a10 = lg1[ln]; a11 = lg1[ln+64]; a12 = lg1[ln+128]; a13 = lg1[ln+192];
        } else {
            a10 = a00; a11 = a01; a12 = a02; a13 = a03;   // defined values, result unused
        }

        float p0 = dot4(a00,w0) + dot4(a01,w1) + dot4(a02,w2) + dot4(a03,w3);
        float p1 = dot4(a10,w0) + dot4(a11,w1) + dot4(a12,w2) + dot4(a13,w3);

        // two independent butterfly reduces, interleaved
        #pragma unroll
        for (int off = 32; off; off >>= 1) {
            p0 += __shfl_xor(p0, off, 64);
            p1 += __shfl_xor(p1, off, 64);
        }

        {
            float o = fminf(fmaxf(p0, LO_C), HI_C);
            if (ln == 0) out_logits[(size_t)b0 * (S_DIM + 1) + s + 1] = o;
            if (b0 == last) {              // wave-uniform; p0 valid in all lanes
                float c = LR_C * (1.0f / (1.0f + expf(-o)) - target[b0]);
                dst[ln]       = upd4(w0, a00, c);
                dst[ln + 64]  = upd4(w1, a01, c);
                dst[ln + 128] = upd4(w2, a02, c);
                dst[ln + 192] = upd4(w3, a03, c);
            }
        }
        if (b1 >= 0) {
            float o = fminf(fmaxf(p1, LO_C), HI_C);
            if (ln == 0) out_logits[(size_t)b1 * (S_DIM + 1) + s + 1] = o;
            if (b1 == last) {
                float c = LR_C * (1.0f / (1.0f + expf(-o)) - target[b1]);
                dst[ln]       = upd4(w0, a10, c);
                dst[ln + 64]  = upd4(w1, a11, c);
                dst[ln + 128] = upd4(w2, a12, c);
                dst[ln + 192] = upd4(w3, a13, c);
            }
        }
    }
}

extern "C" void kernel_launch(void* const* d_in, const int* in_sizes, int n_in,
                              void* d_out, int out_size, void* d_ws, size_t ws_size,
                              hipStream_t stream) {
    const float* logit   = (const float*)d_in[0];   // [B, I, 1]
    const float* context = (const float*)d_in[1];   // [B, CTX]
    const float* target  = (const float*)d_in[2];   // [B, 1]
    const float* cm      = (const float*)d_in[3];   // [1, S, 4, CTX]
    const float* cb      = (const float*)d_in[4];   // [1, S, 4, 1]
    const float* weights = (const float*)d_in[5];   // [1, S, 16, I]
    const float* bias    = (const float*)d_in[6];   // [1]

    float* out_logits  = (float*)d_out;                       // [B, S+1]
    float* new_weights = out_logits + (size_t)B_DIM * (S_DIM + 1);

    char* ws = (char*)d_ws;
    float4* ctxT4 = (float4*)ws;                 ws += (size_t)CTX4 * B_DIM * 16;
    u64*    mask_g  = (u64*)ws;

    prep_kernel<<<CTX4 * B_DIM / 256, 256, 0, stream>>>(context, bias, ctxT4, out_logits);
    gln_idx_kernel<<<S_DIM, 256, 0, stream>>>(cm, cb, ctxT4, mask_g);
    gln_row3_kernel<<<NTASK / 4, 256, 0, stream>>>(logit, target, weights, mask_g,
                                                   out_logits, new_weights);
}